// Round 3
// baseline (1805.688 us; speedup 1.0000x reference)
//
#include <hip/hip_runtime.h>

// GiGCNConv: out[d] = b + (1/deg[d]) * ( h[d] + sum_{e:(s->d)} ew[e]*h[s] )
//   h = x @ W,  deg[d] = 1 + sum_{e:dst==d} ew[e]
//
// Strategy (round 3): coarse bucket binning instead of exact counting sort.
//   bucket = dst >> 6 (64 nodes per bucket, B = ceil(N/64) buckets)
//   1. hist_kernel:  per-block LDS histogram of buckets -> global hist
//   2. bscan_kernel: exclusive scan of hist -> off, cursor (single block)
//   3. bscatter:     pairs[atomic cursor] = {src | (dst&63)<<20, ew}
//                    appends are sequential within each 16KB bucket region
//                    -> cache-line-dense writes (was the 199MB thrash)
//   4. gemm16:       h = x @ W, 16 rows/block, W+x in LDS
//   5. baccum:       one block per bucket; 64x64 f32 accumulator tile in LDS;
//                    stream bucket edges, gather h[src] rows, LDS atomicAdd;
//                    deg accumulated in LDS; one coalesced out-write per node.
//
// Inputs: x f32[N*64], edge_index i32[2*E], edge_weight f32[E],
//         W f32[64*64], b f32[64].  Output f32[N*64].

#define D 64
#define BSHIFT 6                 // 64 nodes per bucket
#define BMAXB 2048               // max buckets supported by hist LDS

// ---------------- bucket histogram ----------------

__global__ __launch_bounds__(256) void hist_kernel(const int* __restrict__ dst,
                                                   int* __restrict__ hist, int E, int B) {
    __shared__ int lh[BMAXB];
    int tid = threadIdx.x;
    for (int i = tid; i < B; i += 256) lh[i] = 0;
    __syncthreads();
    int t = blockIdx.x * blockDim.x + tid;
    int stride = gridDim.x * blockDim.x;
    for (int e = t; e < E; e += stride) atomicAdd(&lh[dst[e] >> BSHIFT], 1);
    __syncthreads();
    for (int i = tid; i < B; i += 256) {
        int v = lh[i];
        if (v) atomicAdd(&hist[i], v);
    }
}

// exclusive scan of hist[0..B) -> off, cursor; off[B] = E. Single block.
__global__ __launch_bounds__(256) void bscan_kernel(const int* __restrict__ hist,
                                                    int* __restrict__ off,
                                                    int* __restrict__ cursor, int B, int E) {
    __shared__ int s[256];
    __shared__ int carry;
    int tid = threadIdx.x;
    if (tid == 0) carry = 0;
    __syncthreads();
    for (int base = 0; base < B; base += 256) {
        int i = base + tid;
        int v = (i < B) ? hist[i] : 0;
        s[tid] = v;
        __syncthreads();
        for (int o = 1; o < 256; o <<= 1) {
            int t = (tid >= o) ? s[tid - o] : 0;
            __syncthreads();
            s[tid] += t;
            __syncthreads();
        }
        int incl = s[tid];
        if (i < B) {
            int ex = carry + incl - v;
            off[i] = ex;
            cursor[i] = ex;
        }
        __syncthreads();
        if (tid == 255) carry += incl;
        __syncthreads();
    }
    if (tid == 0) off[B] = E;
}

// ---------------- binning scatter ----------------

__global__ __launch_bounds__(256) void bscatter_kernel(const int* __restrict__ src,
                                                       const int* __restrict__ dst,
                                                       const float* __restrict__ ew,
                                                       int* __restrict__ cursor,
                                                       int2* __restrict__ pairs, int E) {
    int t = blockIdx.x * blockDim.x + threadIdx.x;
    int stride = gridDim.x * blockDim.x;
    for (int e = t; e < E; e += stride) {
        int d = dst[e];
        int b = d >> BSHIFT;
        int dl = d & (D - 1);
        int pos = atomicAdd(&cursor[b], 1);
        pairs[pos] = make_int2(src[e] | (dl << 20), __float_as_int(ew[e]));
    }
}

// ---------------- h = x @ W (16 rows / block) ----------------

__global__ __launch_bounds__(256) void gemm16_kernel(const float* __restrict__ x,
                                                     const float* __restrict__ W,
                                                     float* __restrict__ h, int N) {
    __shared__ float Ws[D * D];
    __shared__ float xs[16][D];
    int tid = threadIdx.x;
    int j = tid & 63;
    int q = tid >> 6;  // 0..3
    int base = blockIdx.x * 16;
    for (int i = tid; i < D * D; i += 256) Ws[i] = W[i];
    for (int rr = q; rr < 16; rr += 4) {
        int r = base + rr;
        if (r < N) xs[rr][j] = x[(size_t)r * D + j];
    }
    __syncthreads();
    for (int rr = q; rr < 16; rr += 4) {
        int r = base + rr;
        if (r < N) {
            float sum = 0.0f;
#pragma unroll
            for (int k = 0; k < D; ++k) sum = fmaf(xs[rr][k], Ws[k * D + j], sum);
            h[(size_t)r * D + j] = sum;
        }
    }
}

// ---------------- bucket accumulate ----------------

__global__ __launch_bounds__(256) void baccum_kernel(const int2* __restrict__ pairs,
                                                     const int* __restrict__ off,
                                                     const float* __restrict__ h,
                                                     const float* __restrict__ bias,
                                                     float* __restrict__ out, int N) {
    __shared__ float acc[D][D];   // 16 KB
    __shared__ float degs[D];
    int tid = threadIdx.x;
    int lane = tid & 63;
    int wid = tid >> 6;  // 0..3
    int b = blockIdx.x;

    for (int r = wid; r < D; r += 4) acc[r][lane] = 0.0f;
    if (tid < D) degs[tid] = 0.0f;
    __syncthreads();

    int e0 = off[b], e1 = off[b + 1];
    for (int e = e0 + wid; e < e1; e += 4) {
        int2 p = pairs[e];
        int srcn = p.x & 0xFFFFF;
        int dl = p.x >> 20;
        float w = __int_as_float(p.y);
        float hv = h[(size_t)srcn * D + lane];
        atomicAdd(&acc[dl][lane], w * hv);
        if (lane == 0) atomicAdd(&degs[dl], w);
    }
    __syncthreads();

    int gbase = b << BSHIFT;
    for (int r = wid; r < D; r += 4) {
        int g = gbase + r;
        if (g < N) {
            float di = 1.0f / (1.0f + degs[r]);  // deg >= 1 (self loop), ew >= 0
            out[(size_t)g * D + lane] =
                fmaf(di, h[(size_t)g * D + lane] + acc[r][lane], bias[lane]);
        }
    }
}

// ---------------- fallback (atomic scatter) ----------------

__global__ __launch_bounds__(256) void deg_kernel(const int* __restrict__ dst,
                                                  const float* __restrict__ ew,
                                                  float* __restrict__ deg, int E) {
    int t = blockIdx.x * blockDim.x + threadIdx.x;
    int stride = gridDim.x * blockDim.x;
    for (int e = t; e < E; e += stride) atomicAdd(&deg[dst[e]], ew[e]);
}

__global__ __launch_bounds__(256) void deginv_kernel(float* __restrict__ deg, int N) {
    int t = blockIdx.x * blockDim.x + threadIdx.x;
    int stride = gridDim.x * blockDim.x;
    for (int n = t; n < N; n += stride) {
        float tot = deg[n] + 1.0f;
        deg[n] = (tot > 0.0f) ? (1.0f / tot) : 0.0f;
    }
}

__global__ __launch_bounds__(256) void init_kernel(const float* __restrict__ h,
                                                   const float* __restrict__ deginv,
                                                   const float* __restrict__ b,
                                                   float* __restrict__ out, int N) {
    int t = blockIdx.x * blockDim.x + threadIdx.x;
    int stride = gridDim.x * blockDim.x;
    int nq = N * (D / 4);
    const float4* h4 = (const float4*)h;
    const float4* b4 = (const float4*)b;
    float4* o4 = (float4*)out;
    for (int q = t; q < nq; q += stride) {
        int n = q >> 4;
        int c4 = q & 15;
        float4 hv = h4[q];
        float4 bv = b4[c4];
        float di = deginv[n];
        float4 o;
        o.x = bv.x + di * hv.x;
        o.y = bv.y + di * hv.y;
        o.z = bv.z + di * hv.z;
        o.w = bv.w + di * hv.w;
        o4[q] = o;
    }
}

__global__ __launch_bounds__(256) void scatter_kernel(const int* __restrict__ src,
                                                      const int* __restrict__ dst,
                                                      const float* __restrict__ ew,
                                                      const float* __restrict__ deginv,
                                                      const float* __restrict__ h,
                                                      float* __restrict__ out, int E) {
    int t = blockIdx.x * blockDim.x + threadIdx.x;
    int wave = t >> 6;
    int lane = t & 63;
    int nwaves = (gridDim.x * blockDim.x) >> 6;
    for (int e = wave; e < E; e += nwaves) {
        int s = src[e];
        int d = dst[e];
        float norm = deginv[d] * ew[e];
        atomicAdd(&out[d * D + lane], norm * h[s * D + lane]);
    }
}

// ---------------- launcher ----------------

extern "C" void kernel_launch(void* const* d_in, const int* in_sizes, int n_in,
                              void* d_out, int out_size, void* d_ws, size_t ws_size,
                              hipStream_t stream) {
    const float* x  = (const float*)d_in[0];
    const int*   ei = (const int*)d_in[1];
    const float* ew = (const float*)d_in[2];
    const float* W  = (const float*)d_in[3];
    const float* b  = (const float*)d_in[4];
    float* out = (float*)d_out;

    int N = in_sizes[0] / D;
    int E = in_sizes[2];
    const int* srcp = ei;
    const int* dstp = ei + E;

    int B = (N + D - 1) >> BSHIFT;  // buckets

    // ws layout: hist[2048] | off[2112] | cursor[2048] | h[N*D] | pairs[E]
    size_t hdr = (size_t)(2048 + 2112 + 2048);  // ints, 8B-aligned total (25600 B)
    size_t need = hdr * 4 + (size_t)N * D * 4 + (size_t)E * 8;

    if (B <= BMAXB && N < (1 << 20) && ws_size >= need) {
        int* hist   = (int*)d_ws;
        int* off    = hist + 2048;
        int* cursor = off + 2112;
        float* h    = (float*)(cursor + 2048);
        int2* pairs = (int2*)(h + (size_t)N * D);

        hipMemsetAsync(hist, 0, 2048 * 4, stream);
        hist_kernel<<<1024, 256, 0, stream>>>(dstp, hist, E, B);
        bscan_kernel<<<1, 256, 0, stream>>>(hist, off, cursor, B, E);
        bscatter_kernel<<<2048, 256, 0, stream>>>(srcp, dstp, ew, cursor, pairs, E);
        gemm16_kernel<<<(N + 15) / 16, 256, 0, stream>>>(x, W, h, N);
        baccum_kernel<<<B, 256, 0, stream>>>(pairs, off, h, b, out, N);
    } else {
        // fallback: atomic scatter path
        size_t Npad = ((size_t)N + 63) & ~(size_t)63;
        float* deg = (float*)d_ws;
        float* h = deg + Npad;
        hipMemsetAsync(deg, 0, (size_t)N * sizeof(float), stream);
        deg_kernel<<<2048, 256, 0, stream>>>(dstp, ew, deg, E);
        deginv_kernel<<<(N + 255) / 256, 256, 0, stream>>>(deg, N);
        gemm16_kernel<<<(N + 15) / 16, 256, 0, stream>>>(x, W, h, N);
        init_kernel<<<2048, 256, 0, stream>>>(h, deg, b, out, N);
        scatter_kernel<<<2048, 256, 0, stream>>>(srcp, dstp, ew, deg, h, out, E);
    }
}

// Round 4
// 384.551 us; speedup vs baseline: 4.6956x; 4.6956x over previous
//
#include <hip/hip_runtime.h>

// GiGCNConv: out[d] = b + (1/deg[d]) * ( h[d] + sum_{e:(s->d)} ew[e]*h[s] )
//   h = x @ W,  deg[d] = 1 + sum_{e:dst==d} ew[e]
//
// Round-4 pipeline:
//   bucket = dst >> 4 (16 nodes/bucket, B2 = ceil(N/16) ~ 6250)
//   1. hist:    LDS histogram of buckets (8192 bins, 32KB) -> global hist
//   2. bscan:   exclusive scan -> off[B2+1], cursor        (single block)
//   3. bscatter: pairs[atomic cursor[b]] = {src | dl<<20, ew}; writes are
//                line-dense within 4KB bucket regions; cursors 6250-wide
//                (round-3's 1563 hot cursors were the serialization)
//   4. wsort:   wave-per-bucket exact counting sort IN PLACE via LDS tile
//               (<=1024 pairs/bucket), emits node_off[n] per-node offsets.
//               Oversized bucket -> bad[b] flag, accum filters (never on
//               uniform data).
//   5. gemm16:  h = x @ W stored as BF16 (halves gather bytes; error
//               ~1e-3 << 2.5e-2 threshold)
//   6. accum:   wave-per-node (100K waves), register accumulation,
//               unroll x4 gathers, deg computed inline, one write/row.
//
// Inputs: x f32[N*64], edge_index i32[2*E], edge_weight f32[E],
//         W f32[64*64], b f32[64].  Output f32[N*64].

#define D 64
#define BSH 4
#define NBINS 8192
#define CAP 1024

static __device__ __forceinline__ unsigned short f2bf(float f) {
    unsigned u = __float_as_uint(f);
    u += 0x7FFFu + ((u >> 16) & 1u);   // round-to-nearest-even
    return (unsigned short)(u >> 16);
}
static __device__ __forceinline__ float bf2f(unsigned short s) {
    return __uint_as_float(((unsigned)s) << 16);
}

// ---------------- 1. bucket histogram ----------------

__global__ __launch_bounds__(256) void hist_kernel(const int* __restrict__ dst,
                                                   int* __restrict__ hist, int E, int B2) {
    __shared__ int lh[NBINS];
    int tid = threadIdx.x;
    for (int i = tid; i < NBINS; i += 256) lh[i] = 0;
    __syncthreads();
    int t = blockIdx.x * 256 + tid;
    int stride = gridDim.x * 256;
    for (int e = t; e < E; e += stride) atomicAdd(&lh[dst[e] >> BSH], 1);
    __syncthreads();
    for (int i = tid; i < B2; i += 256) {
        int v = lh[i];
        if (v) atomicAdd(&hist[i], v);
    }
}

// ---------------- 2. exclusive scan (single block) ----------------

__global__ __launch_bounds__(256) void bscan_kernel(const int* __restrict__ hist,
                                                    int* __restrict__ off,
                                                    int* __restrict__ cursor, int B2, int E) {
    __shared__ int s[256];
    __shared__ int carry;
    int tid = threadIdx.x;
    if (tid == 0) carry = 0;
    __syncthreads();
    for (int base = 0; base < B2; base += 256) {
        int i = base + tid;
        int v = (i < B2) ? hist[i] : 0;
        s[tid] = v;
        __syncthreads();
        for (int o = 1; o < 256; o <<= 1) {
            int t = (tid >= o) ? s[tid - o] : 0;
            __syncthreads();
            s[tid] += t;
            __syncthreads();
        }
        int incl = s[tid];
        if (i < B2) {
            int ex = carry + incl - v;
            off[i] = ex;
            cursor[i] = ex;
        }
        __syncthreads();
        if (tid == 255) carry += incl;
        __syncthreads();
    }
    if (tid == 0) off[B2] = E;
}

// ---------------- 3. binning scatter ----------------

__global__ __launch_bounds__(256) void bscatter_kernel(const int* __restrict__ src,
                                                       const int* __restrict__ dst,
                                                       const float* __restrict__ ew,
                                                       int* __restrict__ cursor,
                                                       int2* __restrict__ pairs, int E) {
    int t = blockIdx.x * 256 + threadIdx.x;
    int stride = gridDim.x * 256;
    for (int e = t; e < E; e += stride) {
        int d = dst[e];
        int b = d >> BSH;
        int dl = d & 15;
        int pos = atomicAdd(&cursor[b], 1);
        pairs[pos] = make_int2(src[e] | (dl << 20), __float_as_int(ew[e]));
    }
}

// ---------------- 4. wave-per-bucket exact sort (in place) ----------------

__global__ __launch_bounds__(256) void wsort_kernel(const int* __restrict__ off,
                                                    int2* __restrict__ pairs,
                                                    int* __restrict__ node_off,
                                                    int* __restrict__ bad, int B2) {
    __shared__ int2 tile[4][CAP];      // 32 KB
    __shared__ int cnt[4][16];
    __shared__ int excl[4][17];
    __shared__ int cur[4][16];
    int tid = threadIdx.x;
    int lane = tid & 63;
    int w = tid >> 6;
    int b = blockIdx.x * 4 + w;
    bool valid = (b < B2);
    int e0 = valid ? off[b] : 0;
    int e1 = valid ? off[b + 1] : 0;
    int c = e1 - e0;
    bool ok = valid && (c <= CAP);

    if (lane < 16) cnt[w][lane] = 0;
    if (ok) for (int i = lane; i < c; i += 64) tile[w][i] = pairs[e0 + i];
    __syncthreads();
    if (ok) for (int i = lane; i < c; i += 64)
        atomicAdd(&cnt[w][(tile[w][i].x >> 20) & 15], 1);
    __syncthreads();
    if (lane == 0) {
        int run = 0;
        for (int g = 0; g < 16; ++g) { excl[w][g] = ok ? run : 0; run += cnt[w][g]; }
        excl[w][16] = c;               // always bucket total: keeps neighbor writes consistent
        if (valid && !ok) bad[b] = 1;
    }
    __syncthreads();
    if (valid && lane <= 16) node_off[(b << BSH) + lane] = e0 + excl[w][lane];
    if (lane < 16) cur[w][lane] = excl[w][lane];
    __syncthreads();
    if (ok) for (int i = lane; i < c; i += 64) {
        int2 p = tile[w][i];
        int dl = (p.x >> 20) & 15;
        int pos = atomicAdd(&cur[w][dl], 1);
        pairs[e0 + pos] = make_int2(p.x & 0xFFFFF, p.y);   // strip dl
    }
}

// ---------------- 5. h = x @ W -> bf16 ----------------

__global__ __launch_bounds__(256) void gemm16_kernel(const float* __restrict__ x,
                                                     const float* __restrict__ W,
                                                     unsigned short* __restrict__ hbf, int N) {
    __shared__ float Ws[D * D];
    __shared__ float xs[16][D];
    int tid = threadIdx.x;
    int j = tid & 63;
    int q = tid >> 6;
    int base = blockIdx.x * 16;
    for (int i = tid; i < D * D; i += 256) Ws[i] = W[i];
    for (int rr = q; rr < 16; rr += 4) {
        int r = base + rr;
        if (r < N) xs[rr][j] = x[(size_t)r * D + j];
    }
    __syncthreads();
    for (int rr = q; rr < 16; rr += 4) {
        int r = base + rr;
        if (r < N) {
            float sum = 0.0f;
#pragma unroll
            for (int k = 0; k < D; ++k) sum = fmaf(xs[rr][k], Ws[k * D + j], sum);
            hbf[(size_t)r * D + j] = f2bf(sum);
        }
    }
}

// ---------------- 6. accumulate: wave-per-node ----------------

__global__ __launch_bounds__(256) void accum_kernel(const int2* __restrict__ pairs,
                                                    const int* __restrict__ node_off,
                                                    const int* __restrict__ off,
                                                    const int* __restrict__ bad,
                                                    const unsigned short* __restrict__ hbf,
                                                    const float* __restrict__ bias,
                                                    float* __restrict__ out, int N) {
    int t = blockIdx.x * 256 + threadIdx.x;
    int n = t >> 6;
    int j = t & 63;
    if (n >= N) return;
    float acc = bf2f(hbf[(size_t)n * D + j]);   // self loop, weight 1
    float degs = 1.0f;
    int b = n >> BSH;
    if (!bad[b]) {
        int base = node_off[n];
        int c = node_off[n + 1] - base;
        int i = 0;
        for (; i + 3 < c; i += 4) {
            int2 p0 = pairs[base + i];
            int2 p1 = pairs[base + i + 1];
            int2 p2 = pairs[base + i + 2];
            int2 p3 = pairs[base + i + 3];
            float w0 = __int_as_float(p0.y), w1 = __int_as_float(p1.y);
            float w2 = __int_as_float(p2.y), w3 = __int_as_float(p3.y);
            float h0 = bf2f(hbf[(size_t)p0.x * D + j]);
            float h1 = bf2f(hbf[(size_t)p1.x * D + j]);
            float h2 = bf2f(hbf[(size_t)p2.x * D + j]);
            float h3 = bf2f(hbf[(size_t)p3.x * D + j]);
            degs += (w0 + w1) + (w2 + w3);
            acc = fmaf(w0, h0, acc);
            acc = fmaf(w1, h1, acc);
            acc = fmaf(w2, h2, acc);
            acc = fmaf(w3, h3, acc);
        }
        for (; i < c; ++i) {
            int2 p = pairs[base + i];
            float w = __int_as_float(p.y);
            degs += w;
            acc = fmaf(w, bf2f(hbf[(size_t)p.x * D + j]), acc);
        }
    } else {
        // oversized bucket: pairs unsorted (dl still packed) — filter scan
        int e0 = off[b], e1 = off[b + 1];
        int dl = n & 15;
        for (int e = e0; e < e1; ++e) {
            int2 p = pairs[e];
            if (((p.x >> 20) & 15) == dl) {
                float w = __int_as_float(p.y);
                degs += w;
                acc = fmaf(w, bf2f(hbf[(size_t)(p.x & 0xFFFFF) * D + j]), acc);
            }
        }
    }
    float di = (degs > 0.0f) ? (1.0f / degs) : 0.0f;
    out[(size_t)n * D + j] = fmaf(di, acc, bias[j]);
}

// ---------------- fallback (round-1 atomic path) ----------------

__global__ __launch_bounds__(256) void deg_kernel(const int* __restrict__ dst,
                                                  const float* __restrict__ ew,
                                                  float* __restrict__ deg, int E) {
    int t = blockIdx.x * 256 + threadIdx.x;
    int stride = gridDim.x * 256;
    for (int e = t; e < E; e += stride) atomicAdd(&deg[dst[e]], ew[e]);
}

__global__ __launch_bounds__(256) void deginv_kernel(float* __restrict__ deg, int N) {
    int t = blockIdx.x * 256 + threadIdx.x;
    int stride = gridDim.x * 256;
    for (int n = t; n < N; n += stride) {
        float tot = deg[n] + 1.0f;
        deg[n] = (tot > 0.0f) ? (1.0f / tot) : 0.0f;
    }
}

__global__ __launch_bounds__(256) void gemm16f_kernel(const float* __restrict__ x,
                                                      const float* __restrict__ W,
                                                      float* __restrict__ h, int N) {
    __shared__ float Ws[D * D];
    __shared__ float xs[16][D];
    int tid = threadIdx.x;
    int j = tid & 63;
    int q = tid >> 6;
    int base = blockIdx.x * 16;
    for (int i = tid; i < D * D; i += 256) Ws[i] = W[i];
    for (int rr = q; rr < 16; rr += 4) {
        int r = base + rr;
        if (r < N) xs[rr][j] = x[(size_t)r * D + j];
    }
    __syncthreads();
    for (int rr = q; rr < 16; rr += 4) {
        int r = base + rr;
        if (r < N) {
            float sum = 0.0f;
#pragma unroll
            for (int k = 0; k < D; ++k) sum = fmaf(xs[rr][k], Ws[k * D + j], sum);
            h[(size_t)r * D + j] = sum;
        }
    }
}

__global__ __launch_bounds__(256) void init_kernel(const float* __restrict__ h,
                                                   const float* __restrict__ deginv,
                                                   const float* __restrict__ b,
                                                   float* __restrict__ out, int N) {
    int t = blockIdx.x * 256 + threadIdx.x;
    int stride = gridDim.x * 256;
    int nq = N * (D / 4);
    const float4* h4 = (const float4*)h;
    const float4* b4 = (const float4*)b;
    float4* o4 = (float4*)out;
    for (int q = t; q < nq; q += stride) {
        int n = q >> 4;
        int c4 = q & 15;
        float4 hv = h4[q];
        float4 bv = b4[c4];
        float di = deginv[n];
        float4 o;
        o.x = bv.x + di * hv.x;
        o.y = bv.y + di * hv.y;
        o.z = bv.z + di * hv.z;
        o.w = bv.w + di * hv.w;
        o4[q] = o;
    }
}

__global__ __launch_bounds__(256) void scatter_kernel(const int* __restrict__ src,
                                                      const int* __restrict__ dst,
                                                      const float* __restrict__ ew,
                                                      const float* __restrict__ deginv,
                                                      const float* __restrict__ h,
                                                      float* __restrict__ out, int E) {
    int t = blockIdx.x * 256 + threadIdx.x;
    int wave = t >> 6;
    int lane = t & 63;
    int nwaves = (gridDim.x * 256) >> 6;
    for (int e = wave; e < E; e += nwaves) {
        int s = src[e];
        int d = dst[e];
        float norm = deginv[d] * ew[e];
        atomicAdd(&out[d * D + lane], norm * h[s * D + lane]);
    }
}

// ---------------- launcher ----------------

extern "C" void kernel_launch(void* const* d_in, const int* in_sizes, int n_in,
                              void* d_out, int out_size, void* d_ws, size_t ws_size,
                              hipStream_t stream) {
    const float* x  = (const float*)d_in[0];
    const int*   ei = (const int*)d_in[1];
    const float* ew = (const float*)d_in[2];
    const float* W  = (const float*)d_in[3];
    const float* b  = (const float*)d_in[4];
    float* out = (float*)d_out;

    int N = in_sizes[0] / D;
    int E = in_sizes[2];
    const int* srcp = ei;
    const int* dstp = ei + E;

    int B2 = (N + 15) >> BSH;

    // ws layout (ints): hist[NBINS] | cursor[NBINS] | bad[NBINS] | off[NBINS+64] | node_off[B2*16+64]
    // then hbf (N*D ushorts, 128B-aligned), then pairs (E int2, 8B-aligned)
    size_t nodeoff_n = (size_t)B2 * 16 + 64;
    size_t ints_n = (size_t)NBINS * 3 + (NBINS + 64) + nodeoff_n;
    size_t hbf_off = ((ints_n * 4) + 127) & ~(size_t)127;
    size_t pairs_off = (hbf_off + (size_t)N * D * 2 + 7) & ~(size_t)7;
    size_t need = pairs_off + (size_t)E * 8;

    if (B2 <= NBINS && N < (1 << 20) && ws_size >= need) {
        int* hist     = (int*)d_ws;
        int* cursor   = hist + NBINS;
        int* bad      = cursor + NBINS;
        int* off      = bad + NBINS;
        int* node_off = off + NBINS + 64;
        unsigned short* hbf = (unsigned short*)((char*)d_ws + hbf_off);
        int2* pairs   = (int2*)((char*)d_ws + pairs_off);

        hipMemsetAsync(hist, 0, (size_t)NBINS * 3 * 4, stream);  // hist+cursor+bad
        hist_kernel<<<512, 256, 0, stream>>>(dstp, hist, E, B2);
        bscan_kernel<<<1, 256, 0, stream>>>(hist, off, cursor, B2, E);
        bscatter_kernel<<<2048, 256, 0, stream>>>(srcp, dstp, ew, cursor, pairs, E);
        wsort_kernel<<<(B2 + 3) / 4, 256, 0, stream>>>(off, pairs, node_off, bad, B2);
        gemm16_kernel<<<(N + 15) / 16, 256, 0, stream>>>(x, W, hbf, N);
        accum_kernel<<<(N + 3) / 4, 256, 0, stream>>>(pairs, node_off, off, bad, hbf, b, out, N);
    } else {
        // fallback: atomic scatter path
        size_t Npad = ((size_t)N + 63) & ~(size_t)63;
        float* deg = (float*)d_ws;
        float* h = deg + Npad;
        hipMemsetAsync(deg, 0, (size_t)N * sizeof(float), stream);
        deg_kernel<<<2048, 256, 0, stream>>>(dstp, ew, deg, E);
        deginv_kernel<<<(N + 255) / 256, 256, 0, stream>>>(deg, N);
        gemm16f_kernel<<<(N + 15) / 16, 256, 0, stream>>>(x, W, h, N);
        init_kernel<<<2048, 256, 0, stream>>>(h, deg, b, out, N);
        scatter_kernel<<<2048, 256, 0, stream>>>(srcp, dstp, ew, deg, h, out, E);
    }
}